// Round 7
// baseline (211.438 us; speedup 1.0000x reference)
//
#include <hip/hip_runtime.h>
#include <hip/hip_bf16.h>
#include <math.h>

#define Bsz 8
#define Tsz 1024
#define Dsz 768
#define Hn  12
#define Msz (Bsz*Tsz)
#define NQT (Tsz/64)   // 16 q-tiles of 64 rows

typedef __attribute__((ext_vector_type(8))) short bf16x8_t;
typedef __attribute__((ext_vector_type(4))) float f32x4_t;

__device__ __forceinline__ unsigned short f2bf(float f) {
  unsigned u = __builtin_bit_cast(unsigned, f);
  u += 0x7FFFu + ((u >> 16) & 1u);   // RNE (input converts)
  return (unsigned short)(u >> 16);
}

__device__ __forceinline__ unsigned short f2bf_fast(float f) {
  __hip_bfloat16 h = __float2bfloat16(f);
  return __builtin_bit_cast(unsigned short, h);
}

__device__ __forceinline__ void gload16(const void* g, const void* l) {
  __builtin_amdgcn_global_load_lds(
      (const __attribute__((address_space(1))) unsigned int*)g,
      (__attribute__((address_space(3))) unsigned int*)l, 16, 0, 0);
}

// ---------------- fused fp32 -> bf16 convert (x + 4 weights) ----------------
#define XBLKS (Msz*Dsz/1024)        // 6144
#define WBLKS (Dsz*Dsz/1024)        // 576
__global__ __launch_bounds__(256) void cvt_all_kernel(
    const float* __restrict__ x,
    const float* __restrict__ w0, const float* __restrict__ w1,
    const float* __restrict__ w2, const float* __restrict__ w3,
    unsigned short* __restrict__ xb,
    unsigned short* __restrict__ o0, unsigned short* __restrict__ o1,
    unsigned short* __restrict__ o2, unsigned short* __restrict__ o3) {
  int bid = blockIdx.x;
  const float* src; unsigned short* dst; size_t blk;
  if (bid < XBLKS) { src = x; dst = xb; blk = bid; }
  else {
    int t = bid - XBLKS;
    int which = t / WBLKS;
    blk = t % WBLKS;
    switch (which) {
      case 0: src = w0; dst = o0; break;
      case 1: src = w1; dst = o1; break;
      case 2: src = w2; dst = o2; break;
      default: src = w3; dst = o3; break;
    }
  }
  size_t idx = (blk * 256 + threadIdx.x) * 4;
  float4 v = *(const float4*)(src + idx);
  union { unsigned short u[4]; uint2 w; } t;
  t.u[0] = f2bf(v.x); t.u[1] = f2bf(v.y); t.u[2] = f2bf(v.z); t.u[3] = f2bf(v.w);
  *(uint2*)(dst + idx) = t.w;
}

// ---------------- fused QKV GEMM: [Q|K|V] = X * Wcat^T, BK=64 ----------------
// LDS tiles [128][64] bf16 (128B rows) with XOR-16B swizzle (linear LDS dest,
// pre-swizzled global source, swizzled ds_read).
__global__ __launch_bounds__(256) void gemm_qkv_kernel(
    const unsigned short* __restrict__ X, const unsigned short* __restrict__ Wcat,
    unsigned short* __restrict__ Yq, unsigned short* __restrict__ Yk,
    unsigned short* __restrict__ Yvt) {
  __shared__ __align__(16) unsigned short As[128 * 64];
  __shared__ __align__(16) unsigned short Bs[128 * 64];
  const int tid = threadIdx.x;
  const int w = tid >> 6, lane = tid & 63;
  const int i = lane & 15, g = lane >> 4;
  const int wr = w >> 1, wc = w & 1;
  const int bm = blockIdx.x * 128, bn = blockIdx.y * 128;
  const int sr = lane >> 3;                         // row within 8-row chunk
  const int scb = ((lane & 7) * 16) ^ (sr << 4);    // pre-swizzled source col byte

  f32x4_t acc[4][4];
  #pragma unroll
  for (int a = 0; a < 4; ++a)
    #pragma unroll
    for (int b2 = 0; b2 < 4; ++b2)
      #pragma unroll
      for (int r = 0; r < 4; ++r) acc[a][b2][r] = 0.f;

  for (int k0 = 0; k0 < Dsz; k0 += 64) {
    __syncthreads();
    #pragma unroll
    for (int j = 0; j < 4; ++j) {
      const int c = 4 * w + j;                      // chunk 0..15
      const int row = 8 * c + sr;                   // 0..127
      gload16((const char*)X + ((size_t)(bm + row) * Dsz + k0) * 2 + scb,
              (const char*)As + c * 1024);
      gload16((const char*)Wcat + ((size_t)(bn + row) * Dsz + k0) * 2 + scb,
              (const char*)Bs + c * 1024);
    }
    __syncthreads();
    bf16x8_t af[4][2];
    #pragma unroll
    for (int f = 0; f < 4; ++f) {
      const int R = 64 * wr + 16 * f + i;
      #pragma unroll
      for (int kk = 0; kk < 2; ++kk)
        af[f][kk] = *(const bf16x8_t*)((const char*)As + R * 128 +
                                       ((64 * kk + 16 * g) ^ ((i & 7) << 4)));
    }
    #pragma unroll
    for (int b2 = 0; b2 < 4; ++b2) {
      const int R = 64 * wc + 16 * b2 + i;
      const bf16x8_t b0 = *(const bf16x8_t*)((const char*)Bs + R * 128 +
                                             ((16 * g) ^ ((i & 7) << 4)));
      const bf16x8_t b1 = *(const bf16x8_t*)((const char*)Bs + R * 128 +
                                             ((64 + 16 * g) ^ ((i & 7) << 4)));
      #pragma unroll
      for (int a = 0; a < 4; ++a) {
        acc[a][b2] = __builtin_amdgcn_mfma_f32_16x16x32_bf16(af[a][0], b0, acc[a][b2], 0, 0, 0);
        acc[a][b2] = __builtin_amdgcn_mfma_f32_16x16x32_bf16(af[a][1], b1, acc[a][b2], 0, 0, 0);
      }
    }
  }

  const int wsel = blockIdx.y / 6;
  const int nloc = (blockIdx.y % 6) * 128;
  if (wsel < 2) {
    unsigned short* Y = wsel ? Yk : Yq;
    const float sc = wsel ? 1.0f : 0.18033688f;   // Q: 0.125 * log2(e)
    #pragma unroll
    for (int fi = 0; fi < 4; ++fi)
      #pragma unroll
      for (int fj = 0; fj < 4; ++fj) {
        const int n = nloc + 64 * wc + 16 * fj + i;
        #pragma unroll
        for (int r = 0; r < 4; ++r) {
          const int m = bm + 64 * wr + 16 * fi + 4 * g + r;
          Y[(size_t)m * Dsz + n] = f2bf_fast(acc[fi][fj][r] * sc);
        }
      }
  } else {
    #pragma unroll
    for (int fi = 0; fi < 4; ++fi)
      #pragma unroll
      for (int fj = 0; fj < 4; ++fj) {
        const int m0 = bm + 64 * wr + 16 * fi + 4 * g;
        const int bb = m0 >> 10;
        const int t  = m0 & 1023;
        const int n  = nloc + 64 * wc + 16 * fj + i;
        union { unsigned short u[4]; uint2 v; } pk;
        #pragma unroll
        for (int r = 0; r < 4; ++r) pk.u[r] = f2bf_fast(acc[fi][fj][r]);
        *(uint2*)&Yvt[((size_t)(bb * Dsz + n)) * Tsz + t] = pk.v;
      }
  }
}

// ---------------- output projection: out = ctx * Wp^T + bp, BK=64 ----------
__global__ __launch_bounds__(256) void gemm_proj_kernel(
    const unsigned short* __restrict__ X, const unsigned short* __restrict__ W,
    const float* __restrict__ bias, float* __restrict__ Y) {
  __shared__ __align__(16) unsigned short As[128 * 64];
  __shared__ __align__(16) unsigned short Bs[128 * 64];
  const int tid = threadIdx.x;
  const int w = tid >> 6, lane = tid & 63;
  const int i = lane & 15, g = lane >> 4;
  const int wr = w >> 1, wc = w & 1;
  const int bm = blockIdx.x * 128, bn = blockIdx.y * 128;
  const int sr = lane >> 3;
  const int scb = ((lane & 7) * 16) ^ (sr << 4);

  f32x4_t acc[4][4];
  #pragma unroll
  for (int a = 0; a < 4; ++a)
    #pragma unroll
    for (int b2 = 0; b2 < 4; ++b2)
      #pragma unroll
      for (int r = 0; r < 4; ++r) acc[a][b2][r] = 0.f;

  for (int k0 = 0; k0 < Dsz; k0 += 64) {
    __syncthreads();
    #pragma unroll
    for (int j = 0; j < 4; ++j) {
      const int c = 4 * w + j;
      const int row = 8 * c + sr;
      gload16((const char*)X + ((size_t)(bm + row) * Dsz + k0) * 2 + scb,
              (const char*)As + c * 1024);
      gload16((const char*)W + ((size_t)(bn + row) * Dsz + k0) * 2 + scb,
              (const char*)Bs + c * 1024);
    }
    __syncthreads();
    bf16x8_t af[4][2];
    #pragma unroll
    for (int f = 0; f < 4; ++f) {
      const int R = 64 * wr + 16 * f + i;
      #pragma unroll
      for (int kk = 0; kk < 2; ++kk)
        af[f][kk] = *(const bf16x8_t*)((const char*)As + R * 128 +
                                       ((64 * kk + 16 * g) ^ ((i & 7) << 4)));
    }
    #pragma unroll
    for (int b2 = 0; b2 < 4; ++b2) {
      const int R = 64 * wc + 16 * b2 + i;
      const bf16x8_t b0 = *(const bf16x8_t*)((const char*)Bs + R * 128 +
                                             ((16 * g) ^ ((i & 7) << 4)));
      const bf16x8_t b1 = *(const bf16x8_t*)((const char*)Bs + R * 128 +
                                             ((64 + 16 * g) ^ ((i & 7) << 4)));
      #pragma unroll
      for (int a = 0; a < 4; ++a) {
        acc[a][b2] = __builtin_amdgcn_mfma_f32_16x16x32_bf16(af[a][0], b0, acc[a][b2], 0, 0, 0);
        acc[a][b2] = __builtin_amdgcn_mfma_f32_16x16x32_bf16(af[a][1], b1, acc[a][b2], 0, 0, 0);
      }
    }
  }

  #pragma unroll
  for (int fi = 0; fi < 4; ++fi)
    #pragma unroll
    for (int fj = 0; fj < 4; ++fj) {
      const int n = bn + 64 * wc + 16 * fj + i;
      const float bv = bias[n];
      #pragma unroll
      for (int r = 0; r < 4; ++r) {
        const int m = bm + 64 * wr + 16 * fi + 4 * g + r;
        Y[(size_t)m * Dsz + n] = acc[fi][fj][r] + bv;
      }
    }
}

// ---------------- flash attention: 8-wave blocks, shared K/V staging -------
// Block = 512 threads covering 128 q-rows: waves 0-3 -> q-tile 2j (rows
// 128j..128j+63), waves 4-7 -> q-tile 2j+1. One K/V double-buffered staging
// serves both groups; group A skips the final diagonal tile of group B.
// grid = (bh=96, j=8): all 8 j-blocks of a head land on XCD bh%8 (L2 reuse).
__global__ __launch_bounds__(512) void attn_mfma_kernel(
    const unsigned short* __restrict__ Qm, const unsigned short* __restrict__ Km,
    const unsigned short* __restrict__ Vt, unsigned short* __restrict__ ctx) {
  __shared__ __align__(16) unsigned short Ks[2][64 * 64];  // [buf][key][hd] 128B rows
  __shared__ __align__(16) unsigned short Vs[2][64 * 64];  // [buf][hd][key] 128B rows
  __shared__ __align__(16) unsigned short Ps[8][16 * 72];  // per-wave P
  const int tid = threadIdx.x, w = tid >> 6, lane = tid & 63;
  const int i = lane & 15, g = lane >> 4;
  const int grp = w >> 2, wl = w & 3;
  const int bh = blockIdx.x, b = bh / Hn, h = bh % Hn;
  const int j = blockIdx.y;
  const int qt = 2 * j + grp;          // this group's 64-row q-tile index
  const int t0 = qt * 64;
  const int ntB = 2 * j + 2;           // loop bound (group B's tile count)

  const int sr  = lane >> 3;
  const int swz = ((lane & 7) * 16) ^ (sr << 4);

  // Q fragments (A operand) for this wave's 16 q-rows
  bf16x8_t qa[2];
  {
    const unsigned short* qp =
        Qm + ((size_t)(b * Tsz + t0 + 16 * wl + i) * Dsz + h * 64 + 8 * g);
    qa[0] = *(const bf16x8_t*)qp;
    qa[1] = *(const bf16x8_t*)(qp + 32);
  }

  f32x4_t o[4];
  #pragma unroll
  for (int fd = 0; fd < 4; ++fd)
    #pragma unroll
    for (int r = 0; r < 4; ++r) o[fd][r] = 0.f;
  float mrun[4] = {-3.0e38f, -3.0e38f, -3.0e38f, -3.0e38f};
  float lrun[4] = {0.f, 0.f, 0.f, 0.f};

  // stage KV-tile (64 keys at kv0) into buffer p: 8 waves x 1 chunk each
  auto STAGE = [&](int kv0, int p) {
    const int row = 8 * w + sr;
    gload16((const char*)Km + ((size_t)(b * Tsz + kv0 + row) * Dsz + h * 64) * 2 + swz,
            (const char*)Ks[p] + w * 1024);
    gload16((const char*)Vt + ((size_t)(bh * 64 + row) * Tsz + kv0) * 2 + swz,
            (const char*)Vs[p] + w * 1024);
  };

  STAGE(0, 0);
  unsigned short* Pw = &Ps[w][0];

  for (int kt = 0; kt < ntB; ++kt) {
    const int p = kt & 1;
    __syncthreads();   // tile kt staged & visible
    if (kt + 1 < ntB) STAGE((kt + 1) * 64, p ^ 1);

    if (kt <= qt) {    // group-uniform: A skips B's final diagonal tile
      // S = Q K^T : lane holds S[q=4g+r][key=16fj+i]  (log2 units)
      f32x4_t s[4];
      __builtin_amdgcn_s_setprio(1);
      #pragma unroll
      for (int fj = 0; fj < 4; ++fj) {
        #pragma unroll
        for (int r = 0; r < 4; ++r) s[fj][r] = 0.f;
        const int R = 16 * fj + i;
        #pragma unroll
        for (int ks = 0; ks < 2; ++ks) {
          const bf16x8_t kb = *(const bf16x8_t*)((const char*)Ks[p] + R * 128 +
                                                 ((64 * ks + 16 * g) ^ ((i & 7) << 4)));
          s[fj] = __builtin_amdgcn_mfma_f32_16x16x32_bf16(qa[ks], kb, s[fj], 0, 0, 0);
        }
      }
      __builtin_amdgcn_s_setprio(0);

      // causal mask only on this group's diagonal tile
      if (kt == qt) {
        #pragma unroll
        for (int fj = 0; fj < 4; ++fj) {
          const int kidx = kt * 64 + 16 * fj + i;
          #pragma unroll
          for (int r = 0; r < 4; ++r)
            if (kidx > t0 + 16 * wl + 4 * g + r) s[fj][r] = -1.0e30f;
        }
      }

      // row max
      float mx[4];
      #pragma unroll
      for (int r = 0; r < 4; ++r)
        mx[r] = fmaxf(fmaxf(s[0][r], s[1][r]), fmaxf(s[2][r], s[3][r]));
      #pragma unroll
      for (int r = 0; r < 4; ++r) {
        mx[r] = fmaxf(mx[r], __shfl_xor(mx[r], 1));
        mx[r] = fmaxf(mx[r], __shfl_xor(mx[r], 2));
        mx[r] = fmaxf(mx[r], __shfl_xor(mx[r], 4));
        mx[r] = fmaxf(mx[r], __shfl_xor(mx[r], 8));
      }

      // defer-max: rescale only when max grew by >8 (log2 units)
      bool nd = false;
      #pragma unroll
      for (int r = 0; r < 4; ++r) nd = nd || (mx[r] > mrun[r] + 8.0f);
      if (__any(nd)) {
        #pragma unroll
        for (int r = 0; r < 4; ++r) {
          const float mn = fmaxf(mrun[r], mx[r]);
          const float fs = exp2f(mrun[r] - mn);
          mrun[r] = mn;
          lrun[r] *= fs;
          #pragma unroll
          for (int fd = 0; fd < 4; ++fd) o[fd][r] *= fs;
        }
      }

      float rs[4] = {0.f, 0.f, 0.f, 0.f};
      #pragma unroll
      for (int fj = 0; fj < 4; ++fj)
        #pragma unroll
        for (int r = 0; r < 4; ++r) {
          s[fj][r] = exp2f(s[fj][r] - mrun[r]);
          rs[r] += s[fj][r];
        }
      #pragma unroll
      for (int r = 0; r < 4; ++r) {
        rs[r] += __shfl_xor(rs[r], 1);
        rs[r] += __shfl_xor(rs[r], 2);
        rs[r] += __shfl_xor(rs[r], 4);
        rs[r] += __shfl_xor(rs[r], 8);
        lrun[r] += rs[r];
      }

      // stage P (bf16) into private per-wave buffer, layout D->A
      #pragma unroll
      for (int fj = 0; fj < 4; ++fj)
        #pragma unroll
        for (int r = 0; r < 4; ++r)
          Pw[(4 * g + r) * 72 + 16 * fj + i] = f2bf_fast(s[fj][r]);

      // O += P * V
      __builtin_amdgcn_s_setprio(1);
      #pragma unroll
      for (int ks = 0; ks < 2; ++ks) {
        const bf16x8_t pa = *(const bf16x8_t*)&Pw[i * 72 + 32 * ks + 8 * g];
        #pragma unroll
        for (int fd = 0; fd < 4; ++fd) {
          const int R = 16 * fd + i;
          const bf16x8_t vb = *(const bf16x8_t*)((const char*)Vs[p] + R * 128 +
                                                 ((64 * ks + 16 * g) ^ ((i & 7) << 4)));
          o[fd] = __builtin_amdgcn_mfma_f32_16x16x32_bf16(pa, vb, o[fd], 0, 0, 0);
        }
      }
      __builtin_amdgcn_s_setprio(0);
    }
  }

  // epilogue: this wave's 16 q-rows
  #pragma unroll
  for (int r = 0; r < 4; ++r) {
    const float inv = 1.f / lrun[r];
    const int qidx = t0 + 16 * wl + 4 * g + r;
    #pragma unroll
    for (int fd = 0; fd < 4; ++fd)
      ctx[(size_t)(b * Tsz + qidx) * Dsz + h * 64 + 16 * fd + i] =
          f2bf_fast(o[fd][r] * inv);
  }
}

extern "C" void kernel_launch(void* const* d_in, const int* in_sizes, int n_in,
                              void* d_out, int out_size, void* d_ws, size_t ws_size,
                              hipStream_t stream) {
  const float* x  = (const float*)d_in[0];
  const float* Wq = (const float*)d_in[1];
  const float* Wk = (const float*)d_in[2];
  const float* Wv = (const float*)d_in[3];
  const float* Wp = (const float*)d_in[4];
  const float* bp = (const float*)d_in[5];
  float* out = (float*)d_out;

  const size_t md = (size_t)Msz * Dsz;
  const size_t wd = (size_t)Dsz * Dsz;
  unsigned short* xb   = (unsigned short*)d_ws;
  unsigned short* wqb  = xb + md;          // wqb,wkb,wvb contiguous = Wcat[2304][768]
  unsigned short* wkb  = wqb + wd;
  unsigned short* wvb  = wkb + wd;
  unsigned short* wpb  = wvb + wd;
  unsigned short* qb   = wpb + wd;
  unsigned short* kb   = qb + md;
  unsigned short* vtb  = kb + md;
  unsigned short* ctxb = vtb + md;

  cvt_all_kernel<<<XBLKS + 4 * WBLKS, 256, 0, stream>>>(
      x, Wq, Wk, Wv, Wp, xb, wqb, wkb, wvb, wpb);

  gemm_qkv_kernel<<<dim3(Msz / 128, 18), 256, 0, stream>>>(xb, wqb, qb, kb, vtb);

  attn_mfma_kernel<<<dim3(Bsz * Hn, 8), 512, 0, stream>>>(qb, kb, vtb, ctxb);

  gemm_proj_kernel<<<dim3(Msz / 128, Dsz / 128), 256, 0, stream>>>(ctxb, wpb, bp, out);
}

// Round 8
// 202.195 us; speedup vs baseline: 1.0457x; 1.0457x over previous
//
#include <hip/hip_runtime.h>
#include <hip/hip_bf16.h>
#include <math.h>

#define Bsz 8
#define Tsz 1024
#define Dsz 768
#define Hn  12
#define Msz (Bsz*Tsz)
#define NQT (Tsz/64)   // 16 q-tiles of 64 rows

typedef __attribute__((ext_vector_type(8))) short bf16x8_t;
typedef __attribute__((ext_vector_type(4))) float f32x4_t;

// VALU cross-lane via DPP (16-lane-group butterfly): 0xB1=xor1, 0x4E=xor2,
// 0x141=row_half_mirror (combines 4-groups), 0x140=row_mirror (combines 8s).
#define DPPF(v, CTRL) __builtin_bit_cast(float, __builtin_amdgcn_update_dpp( \
    0, __builtin_bit_cast(int, (v)), (CTRL), 0xF, 0xF, true))

__device__ __forceinline__ unsigned short f2bf(float f) {
  unsigned u = __builtin_bit_cast(unsigned, f);
  u += 0x7FFFu + ((u >> 16) & 1u);   // RNE (input converts)
  return (unsigned short)(u >> 16);
}

__device__ __forceinline__ unsigned short f2bf_fast(float f) {
  __hip_bfloat16 h = __float2bfloat16(f);
  return __builtin_bit_cast(unsigned short, h);
}

__device__ __forceinline__ void gload16(const void* g, const void* l) {
  __builtin_amdgcn_global_load_lds(
      (const __attribute__((address_space(1))) unsigned int*)g,
      (__attribute__((address_space(3))) unsigned int*)l, 16, 0, 0);
}

// ---------------- fused fp32 -> bf16 convert (x + 4 weights) ----------------
#define XBLKS (Msz*Dsz/1024)        // 6144
#define WBLKS (Dsz*Dsz/1024)        // 576
__global__ __launch_bounds__(256) void cvt_all_kernel(
    const float* __restrict__ x,
    const float* __restrict__ w0, const float* __restrict__ w1,
    const float* __restrict__ w2, const float* __restrict__ w3,
    unsigned short* __restrict__ xb,
    unsigned short* __restrict__ o0, unsigned short* __restrict__ o1,
    unsigned short* __restrict__ o2, unsigned short* __restrict__ o3) {
  int bid = blockIdx.x;
  const float* src; unsigned short* dst; size_t blk;
  if (bid < XBLKS) { src = x; dst = xb; blk = bid; }
  else {
    int t = bid - XBLKS;
    int which = t / WBLKS;
    blk = t % WBLKS;
    switch (which) {
      case 0: src = w0; dst = o0; break;
      case 1: src = w1; dst = o1; break;
      case 2: src = w2; dst = o2; break;
      default: src = w3; dst = o3; break;
    }
  }
  size_t idx = (blk * 256 + threadIdx.x) * 4;
  float4 v = *(const float4*)(src + idx);
  union { unsigned short u[4]; uint2 w; } t;
  t.u[0] = f2bf(v.x); t.u[1] = f2bf(v.y); t.u[2] = f2bf(v.z); t.u[3] = f2bf(v.w);
  *(uint2*)(dst + idx) = t.w;
}

// ---------------- fused QKV GEMM: [Q|K|V] = X * Wcat^T, BK=64 ----------------
__global__ __launch_bounds__(256) void gemm_qkv_kernel(
    const unsigned short* __restrict__ X, const unsigned short* __restrict__ Wcat,
    unsigned short* __restrict__ Yq, unsigned short* __restrict__ Yk,
    unsigned short* __restrict__ Yvt) {
  __shared__ __align__(16) unsigned short As[128 * 64];
  __shared__ __align__(16) unsigned short Bs[128 * 64];
  const int tid = threadIdx.x;
  const int w = tid >> 6, lane = tid & 63;
  const int i = lane & 15, g = lane >> 4;
  const int wr = w >> 1, wc = w & 1;
  const int bm = blockIdx.x * 128, bn = blockIdx.y * 128;
  const int sr = lane >> 3;                         // row within 8-row chunk
  const int scb = ((lane & 7) * 16) ^ (sr << 4);    // pre-swizzled source col byte

  f32x4_t acc[4][4];
  #pragma unroll
  for (int a = 0; a < 4; ++a)
    #pragma unroll
    for (int b2 = 0; b2 < 4; ++b2)
      #pragma unroll
      for (int r = 0; r < 4; ++r) acc[a][b2][r] = 0.f;

  for (int k0 = 0; k0 < Dsz; k0 += 64) {
    __syncthreads();
    #pragma unroll
    for (int j = 0; j < 4; ++j) {
      const int c = 4 * w + j;                      // chunk 0..15
      const int row = 8 * c + sr;                   // 0..127
      gload16((const char*)X + ((size_t)(bm + row) * Dsz + k0) * 2 + scb,
              (const char*)As + c * 1024);
      gload16((const char*)Wcat + ((size_t)(bn + row) * Dsz + k0) * 2 + scb,
              (const char*)Bs + c * 1024);
    }
    __syncthreads();
    bf16x8_t af[4][2];
    #pragma unroll
    for (int f = 0; f < 4; ++f) {
      const int R = 64 * wr + 16 * f + i;
      #pragma unroll
      for (int kk = 0; kk < 2; ++kk)
        af[f][kk] = *(const bf16x8_t*)((const char*)As + R * 128 +
                                       ((64 * kk + 16 * g) ^ ((i & 7) << 4)));
    }
    #pragma unroll
    for (int b2 = 0; b2 < 4; ++b2) {
      const int R = 64 * wc + 16 * b2 + i;
      const bf16x8_t b0 = *(const bf16x8_t*)((const char*)Bs + R * 128 +
                                             ((16 * g) ^ ((i & 7) << 4)));
      const bf16x8_t b1 = *(const bf16x8_t*)((const char*)Bs + R * 128 +
                                             ((64 + 16 * g) ^ ((i & 7) << 4)));
      #pragma unroll
      for (int a = 0; a < 4; ++a) {
        acc[a][b2] = __builtin_amdgcn_mfma_f32_16x16x32_bf16(af[a][0], b0, acc[a][b2], 0, 0, 0);
        acc[a][b2] = __builtin_amdgcn_mfma_f32_16x16x32_bf16(af[a][1], b1, acc[a][b2], 0, 0, 0);
      }
    }
  }

  const int wsel = blockIdx.y / 6;
  const int nloc = (blockIdx.y % 6) * 128;
  if (wsel < 2) {
    unsigned short* Y = wsel ? Yk : Yq;
    const float sc = wsel ? 1.0f : 0.18033688f;   // Q: 0.125 * log2(e)
    #pragma unroll
    for (int fi = 0; fi < 4; ++fi)
      #pragma unroll
      for (int fj = 0; fj < 4; ++fj) {
        const int n = nloc + 64 * wc + 16 * fj + i;
        #pragma unroll
        for (int r = 0; r < 4; ++r) {
          const int m = bm + 64 * wr + 16 * fi + 4 * g + r;
          Y[(size_t)m * Dsz + n] = f2bf_fast(acc[fi][fj][r] * sc);
        }
      }
  } else {
    #pragma unroll
    for (int fi = 0; fi < 4; ++fi)
      #pragma unroll
      for (int fj = 0; fj < 4; ++fj) {
        const int m0 = bm + 64 * wr + 16 * fi + 4 * g;
        const int bb = m0 >> 10;
        const int t  = m0 & 1023;
        const int n  = nloc + 64 * wc + 16 * fj + i;
        union { unsigned short u[4]; uint2 v; } pk;
        #pragma unroll
        for (int r = 0; r < 4; ++r) pk.u[r] = f2bf_fast(acc[fi][fj][r]);
        *(uint2*)&Yvt[((size_t)(bb * Dsz + n)) * Tsz + t] = pk.v;
      }
  }
}

// ---------------- output projection: out = ctx * Wp^T + bp, BK=64 ----------
__global__ __launch_bounds__(256) void gemm_proj_kernel(
    const unsigned short* __restrict__ X, const unsigned short* __restrict__ W,
    const float* __restrict__ bias, float* __restrict__ Y) {
  __shared__ __align__(16) unsigned short As[128 * 64];
  __shared__ __align__(16) unsigned short Bs[128 * 64];
  const int tid = threadIdx.x;
  const int w = tid >> 6, lane = tid & 63;
  const int i = lane & 15, g = lane >> 4;
  const int wr = w >> 1, wc = w & 1;
  const int bm = blockIdx.x * 128, bn = blockIdx.y * 128;
  const int sr = lane >> 3;
  const int scb = ((lane & 7) * 16) ^ (sr << 4);

  f32x4_t acc[4][4];
  #pragma unroll
  for (int a = 0; a < 4; ++a)
    #pragma unroll
    for (int b2 = 0; b2 < 4; ++b2)
      #pragma unroll
      for (int r = 0; r < 4; ++r) acc[a][b2][r] = 0.f;

  for (int k0 = 0; k0 < Dsz; k0 += 64) {
    __syncthreads();
    #pragma unroll
    for (int j = 0; j < 4; ++j) {
      const int c = 4 * w + j;
      const int row = 8 * c + sr;
      gload16((const char*)X + ((size_t)(bm + row) * Dsz + k0) * 2 + scb,
              (const char*)As + c * 1024);
      gload16((const char*)W + ((size_t)(bn + row) * Dsz + k0) * 2 + scb,
              (const char*)Bs + c * 1024);
    }
    __syncthreads();
    bf16x8_t af[4][2];
    #pragma unroll
    for (int f = 0; f < 4; ++f) {
      const int R = 64 * wr + 16 * f + i;
      #pragma unroll
      for (int kk = 0; kk < 2; ++kk)
        af[f][kk] = *(const bf16x8_t*)((const char*)As + R * 128 +
                                       ((64 * kk + 16 * g) ^ ((i & 7) << 4)));
    }
    #pragma unroll
    for (int b2 = 0; b2 < 4; ++b2) {
      const int R = 64 * wc + 16 * b2 + i;
      const bf16x8_t b0 = *(const bf16x8_t*)((const char*)Bs + R * 128 +
                                             ((16 * g) ^ ((i & 7) << 4)));
      const bf16x8_t b1 = *(const bf16x8_t*)((const char*)Bs + R * 128 +
                                             ((64 + 16 * g) ^ ((i & 7) << 4)));
      #pragma unroll
      for (int a = 0; a < 4; ++a) {
        acc[a][b2] = __builtin_amdgcn_mfma_f32_16x16x32_bf16(af[a][0], b0, acc[a][b2], 0, 0, 0);
        acc[a][b2] = __builtin_amdgcn_mfma_f32_16x16x32_bf16(af[a][1], b1, acc[a][b2], 0, 0, 0);
      }
    }
  }

  #pragma unroll
  for (int fi = 0; fi < 4; ++fi)
    #pragma unroll
    for (int fj = 0; fj < 4; ++fj) {
      const int n = bn + 64 * wc + 16 * fj + i;
      const float bv = bias[n];
      #pragma unroll
      for (int r = 0; r < 4; ++r) {
        const int m = bm + 64 * wr + 16 * fi + 4 * g + r;
        Y[(size_t)m * Dsz + n] = acc[fi][fj][r] + bv;
      }
    }
}

// ---------------- flash attention: 8-wave blocks, BALANCED pairing ---------
// Block = 512 threads: waves 0-3 (group A) -> q-tile j, waves 4-7 (group B)
// -> q-tile 15-j. Loop kt=0..15-j over shared double-buffered K/V staging;
// group A computes only while kt<=j. Active wave-tile units = 17 per block
// (constant) -> balanced makespan, halved K/V fetch preserved.
// Softmax: DPP (VALU) max-butterfly; lrun kept as PER-LANE PARTIAL, reduced
// once per q-tile in the epilogue (removes per-tile sum shuffles).
__global__ __launch_bounds__(512) void attn_mfma_kernel(
    const unsigned short* __restrict__ Qm, const unsigned short* __restrict__ Km,
    const unsigned short* __restrict__ Vt, unsigned short* __restrict__ ctx) {
  __shared__ __align__(16) unsigned short Ks[2][64 * 64];  // [buf][key][hd]
  __shared__ __align__(16) unsigned short Vs[2][64 * 64];  // [buf][hd][key]
  __shared__ __align__(16) unsigned short Ps[8][16 * 72];  // per-wave P
  const int tid = threadIdx.x, w = tid >> 6, lane = tid & 63;
  const int i = lane & 15, g = lane >> 4;
  const int grp = w >> 2, wl = w & 3;
  const int bh = blockIdx.x, b = bh / Hn, h = bh % Hn;
  const int j = blockIdx.y;
  const int qt = grp ? (NQT - 1 - j) : j;   // A: tile j, B: tile 15-j
  const int t0 = qt * 64;
  const int nkt = NQT - j;                  // loop bound (group B's tiles)

  const int sr  = lane >> 3;
  const int swz = ((lane & 7) * 16) ^ (sr << 4);

  // Q fragments (A operand) for this wave's 16 q-rows
  bf16x8_t qa[2];
  {
    const unsigned short* qp =
        Qm + ((size_t)(b * Tsz + t0 + 16 * wl + i) * Dsz + h * 64 + 8 * g);
    qa[0] = *(const bf16x8_t*)qp;
    qa[1] = *(const bf16x8_t*)(qp + 32);
  }

  f32x4_t o[4];
  #pragma unroll
  for (int fd = 0; fd < 4; ++fd)
    #pragma unroll
    for (int r = 0; r < 4; ++r) o[fd][r] = 0.f;
  float mrun[4] = {-3.0e38f, -3.0e38f, -3.0e38f, -3.0e38f};
  float lrun[4] = {0.f, 0.f, 0.f, 0.f};   // per-lane partial row-sums

  // stage KV-tile (64 keys at kv0) into buffer p: 8 waves x 1 chunk each
  auto STAGE = [&](int kv0, int p) {
    const int row = 8 * w + sr;
    gload16((const char*)Km + ((size_t)(b * Tsz + kv0 + row) * Dsz + h * 64) * 2 + swz,
            (const char*)Ks[p] + w * 1024);
    gload16((const char*)Vt + ((size_t)(bh * 64 + row) * Tsz + kv0) * 2 + swz,
            (const char*)Vs[p] + w * 1024);
  };

  STAGE(0, 0);
  unsigned short* Pw = &Ps[w][0];

  for (int kt = 0; kt < nkt; ++kt) {
    const int p = kt & 1;
    __syncthreads();   // tile kt staged & visible
    if (kt + 1 < nkt) STAGE((kt + 1) * 64, p ^ 1);

    if (kt <= qt) {    // group-uniform: A idles once kt passes its tile
      // S = Q K^T : lane holds S[q=4g+r][key=16fj+i]  (log2 units)
      f32x4_t s[4];
      __builtin_amdgcn_s_setprio(1);
      #pragma unroll
      for (int fj = 0; fj < 4; ++fj) {
        #pragma unroll
        for (int r = 0; r < 4; ++r) s[fj][r] = 0.f;
        const int R = 16 * fj + i;
        #pragma unroll
        for (int ks = 0; ks < 2; ++ks) {
          const bf16x8_t kb = *(const bf16x8_t*)((const char*)Ks[p] + R * 128 +
                                                 ((64 * ks + 16 * g) ^ ((i & 7) << 4)));
          s[fj] = __builtin_amdgcn_mfma_f32_16x16x32_bf16(qa[ks], kb, s[fj], 0, 0, 0);
        }
      }
      __builtin_amdgcn_s_setprio(0);

      // causal mask only on this group's diagonal tile
      if (kt == qt) {
        #pragma unroll
        for (int fj = 0; fj < 4; ++fj) {
          const int kidx = kt * 64 + 16 * fj + i;
          #pragma unroll
          for (int r = 0; r < 4; ++r)
            if (kidx > t0 + 16 * wl + 4 * g + r) s[fj][r] = -1.0e30f;
        }
      }

      // row max: in-lane over 4 fj, then DPP butterfly across the 16-group
      float mx[4];
      #pragma unroll
      for (int r = 0; r < 4; ++r) {
        float v = fmaxf(fmaxf(s[0][r], s[1][r]), fmaxf(s[2][r], s[3][r]));
        v = fmaxf(v, DPPF(v, 0xB1));    // xor1 (quad_perm 1,0,3,2)
        v = fmaxf(v, DPPF(v, 0x4E));    // xor2 (quad_perm 2,3,0,1)
        v = fmaxf(v, DPPF(v, 0x141));   // row_half_mirror: merge quads
        v = fmaxf(v, DPPF(v, 0x140));   // row_mirror: merge halves
        mx[r] = v;
      }

      // defer-max: rescale only when max grew by >8 (log2 units)
      bool nd = false;
      #pragma unroll
      for (int r = 0; r < 4; ++r) nd = nd || (mx[r] > mrun[r] + 8.0f);
      if (__any(nd)) {
        #pragma unroll
        for (int r = 0; r < 4; ++r) {
          const float mn = fmaxf(mrun[r], mx[r]);
          const float fs = exp2f(mrun[r] - mn);
          mrun[r] = mn;
          lrun[r] *= fs;                 // per-lane partial: linear, commutes
          #pragma unroll
          for (int fd = 0; fd < 4; ++fd) o[fd][r] *= fs;
        }
      }

      // exponentiate + accumulate per-lane partial sums (NO cross-lane here)
      #pragma unroll
      for (int fj = 0; fj < 4; ++fj)
        #pragma unroll
        for (int r = 0; r < 4; ++r) {
          s[fj][r] = exp2f(s[fj][r] - mrun[r]);
          lrun[r] += s[fj][r];
        }

      // stage P (bf16) into private per-wave buffer, layout D->A
      #pragma unroll
      for (int fj = 0; fj < 4; ++fj)
        #pragma unroll
        for (int r = 0; r < 4; ++r)
          Pw[(4 * g + r) * 72 + 16 * fj + i] = f2bf_fast(s[fj][r]);

      // O += P * V
      __builtin_amdgcn_s_setprio(1);
      #pragma unroll
      for (int ks = 0; ks < 2; ++ks) {
        const bf16x8_t pa = *(const bf16x8_t*)&Pw[i * 72 + 32 * ks + 8 * g];
        #pragma unroll
        for (int fd = 0; fd < 4; ++fd) {
          const int R = 16 * fd + i;
          const bf16x8_t vb = *(const bf16x8_t*)((const char*)Vs[p] + R * 128 +
                                                 ((64 * ks + 16 * g) ^ ((i & 7) << 4)));
          o[fd] = __builtin_amdgcn_mfma_f32_16x16x32_bf16(pa, vb, o[fd], 0, 0, 0);
        }
      }
      __builtin_amdgcn_s_setprio(0);
    }
  }

  // epilogue: reduce per-lane partials once, then write this wave's 16 q-rows
  #pragma unroll
  for (int r = 0; r < 4; ++r) {
    float l = lrun[r];
    l += DPPF(l, 0xB1);
    l += DPPF(l, 0x4E);
    l += DPPF(l, 0x141);
    l += DPPF(l, 0x140);
    const float inv = 1.f / l;
    const int qidx = t0 + 16 * wl + 4 * g + r;
    #pragma unroll
    for (int fd = 0; fd < 4; ++fd)
      ctx[(size_t)(b * Tsz + qidx) * Dsz + h * 64 + 16 * fd + i] =
          f2bf_fast(o[fd][r] * inv);
  }
}

extern "C" void kernel_launch(void* const* d_in, const int* in_sizes, int n_in,
                              void* d_out, int out_size, void* d_ws, size_t ws_size,
                              hipStream_t stream) {
  const float* x  = (const float*)d_in[0];
  const float* Wq = (const float*)d_in[1];
  const float* Wk = (const float*)d_in[2];
  const float* Wv = (const float*)d_in[3];
  const float* Wp = (const float*)d_in[4];
  const float* bp = (const float*)d_in[5];
  float* out = (float*)d_out;

  const size_t md = (size_t)Msz * Dsz;
  const size_t wd = (size_t)Dsz * Dsz;
  unsigned short* xb   = (unsigned short*)d_ws;
  unsigned short* wqb  = xb + md;          // wqb,wkb,wvb contiguous = Wcat[2304][768]
  unsigned short* wkb  = wqb + wd;
  unsigned short* wvb  = wkb + wd;
  unsigned short* wpb  = wvb + wd;
  unsigned short* qb   = wpb + wd;
  unsigned short* kb   = qb + md;
  unsigned short* vtb  = kb + md;
  unsigned short* ctxb = vtb + md;

  cvt_all_kernel<<<XBLKS + 4 * WBLKS, 256, 0, stream>>>(
      x, Wq, Wk, Wv, Wp, xb, wqb, wkb, wvb, wpb);

  gemm_qkv_kernel<<<dim3(Msz / 128, 18), 256, 0, stream>>>(xb, wqb, qb, kb, vtb);

  attn_mfma_kernel<<<dim3(Bsz * Hn, 8), 512, 0, stream>>>(qb, kb, vtb, ctxb);

  gemm_proj_kernel<<<dim3(Msz / 128, Dsz / 128), 256, 0, stream>>>(ctxb, wpb, bp, out);
}

// Round 9
// 200.385 us; speedup vs baseline: 1.0552x; 1.0090x over previous
//
#include <hip/hip_runtime.h>
#include <hip/hip_bf16.h>
#include <math.h>

#define Bsz 8
#define Tsz 1024
#define Dsz 768
#define Hn  12
#define Msz (Bsz*Tsz)
#define NQT (Tsz/64)   // 16 q-tiles of 64 rows

typedef __attribute__((ext_vector_type(8))) short bf16x8_t;
typedef __attribute__((ext_vector_type(4))) float f32x4_t;

// VALU cross-lane via DPP (16-lane-group butterfly)
#define DPPF(v, CTRL) __builtin_bit_cast(float, __builtin_amdgcn_update_dpp( \
    0, __builtin_bit_cast(int, (v)), (CTRL), 0xF, 0xF, true))

__device__ __forceinline__ unsigned short f2bf(float f) {
  unsigned u = __builtin_bit_cast(unsigned, f);
  u += 0x7FFFu + ((u >> 16) & 1u);   // RNE (input converts)
  return (unsigned short)(u >> 16);
}

__device__ __forceinline__ unsigned short f2bf_fast(float f) {
  __hip_bfloat16 h = __float2bfloat16(f);
  return __builtin_bit_cast(unsigned short, h);
}

__device__ __forceinline__ void gload16(const void* g, const void* l) {
  __builtin_amdgcn_global_load_lds(
      (const __attribute__((address_space(1))) unsigned int*)g,
      (__attribute__((address_space(3))) unsigned int*)l, 16, 0, 0);
}

// ---------------- fused fp32 -> bf16 convert (x + 4 weights) ----------------
#define XBLKS (Msz*Dsz/1024)        // 6144
#define WBLKS (Dsz*Dsz/1024)        // 576
__global__ __launch_bounds__(256) void cvt_all_kernel(
    const float* __restrict__ x,
    const float* __restrict__ w0, const float* __restrict__ w1,
    const float* __restrict__ w2, const float* __restrict__ w3,
    unsigned short* __restrict__ xb,
    unsigned short* __restrict__ o0, unsigned short* __restrict__ o1,
    unsigned short* __restrict__ o2, unsigned short* __restrict__ o3) {
  int bid = blockIdx.x;
  const float* src; unsigned short* dst; size_t blk;
  if (bid < XBLKS) { src = x; dst = xb; blk = bid; }
  else {
    int t = bid - XBLKS;
    int which = t / WBLKS;
    blk = t % WBLKS;
    switch (which) {
      case 0: src = w0; dst = o0; break;
      case 1: src = w1; dst = o1; break;
      case 2: src = w2; dst = o2; break;
      default: src = w3; dst = o3; break;
    }
  }
  size_t idx = (blk * 256 + threadIdx.x) * 4;
  float4 v = *(const float4*)(src + idx);
  union { unsigned short u[4]; uint2 w; } t;
  t.u[0] = f2bf(v.x); t.u[1] = f2bf(v.y); t.u[2] = f2bf(v.z); t.u[3] = f2bf(v.w);
  *(uint2*)(dst + idx) = t.w;
}

// ---------------- fused QKV GEMM: [Q|K|V] = X * Wcat^T, BK=64 ----------------
// V-epilogue assembles the [n][t] tile in LDS (reusing staging buffers) and
// writes 16B-contiguous runs instead of 8B scatters at 2KB stride.
__global__ __launch_bounds__(256) void gemm_qkv_kernel(
    const unsigned short* __restrict__ X, const unsigned short* __restrict__ Wcat,
    unsigned short* __restrict__ Yq, unsigned short* __restrict__ Yk,
    unsigned short* __restrict__ Yvt) {
  __shared__ __align__(16) unsigned short SMEM[2 * 128 * 64];  // As | Bs (32 KB)
  unsigned short* As = SMEM;
  unsigned short* Bs = SMEM + 128 * 64;
  const int tid = threadIdx.x;
  const int w = tid >> 6, lane = tid & 63;
  const int i = lane & 15, g = lane >> 4;
  const int wr = w >> 1, wc = w & 1;
  const int bm = blockIdx.x * 128, bn = blockIdx.y * 128;
  const int sr = lane >> 3;                         // row within 8-row chunk
  const int scb = ((lane & 7) * 16) ^ (sr << 4);    // pre-swizzled source col byte

  f32x4_t acc[4][4];
  #pragma unroll
  for (int a = 0; a < 4; ++a)
    #pragma unroll
    for (int b2 = 0; b2 < 4; ++b2)
      #pragma unroll
      for (int r = 0; r < 4; ++r) acc[a][b2][r] = 0.f;

  for (int k0 = 0; k0 < Dsz; k0 += 64) {
    __syncthreads();
    #pragma unroll
    for (int j = 0; j < 4; ++j) {
      const int c = 4 * w + j;                      // chunk 0..15
      const int row = 8 * c + sr;                   // 0..127
      gload16((const char*)X + ((size_t)(bm + row) * Dsz + k0) * 2 + scb,
              (const char*)As + c * 1024);
      gload16((const char*)Wcat + ((size_t)(bn + row) * Dsz + k0) * 2 + scb,
              (const char*)Bs + c * 1024);
    }
    __syncthreads();
    bf16x8_t af[4][2];
    #pragma unroll
    for (int f = 0; f < 4; ++f) {
      const int R = 64 * wr + 16 * f + i;
      #pragma unroll
      for (int kk = 0; kk < 2; ++kk)
        af[f][kk] = *(const bf16x8_t*)((const char*)As + R * 128 +
                                       ((64 * kk + 16 * g) ^ ((i & 7) << 4)));
    }
    #pragma unroll
    for (int b2 = 0; b2 < 4; ++b2) {
      const int R = 64 * wc + 16 * b2 + i;
      const bf16x8_t b0 = *(const bf16x8_t*)((const char*)Bs + R * 128 +
                                             ((16 * g) ^ ((i & 7) << 4)));
      const bf16x8_t b1 = *(const bf16x8_t*)((const char*)Bs + R * 128 +
                                             ((64 + 16 * g) ^ ((i & 7) << 4)));
      #pragma unroll
      for (int a = 0; a < 4; ++a) {
        acc[a][b2] = __builtin_amdgcn_mfma_f32_16x16x32_bf16(af[a][0], b0, acc[a][b2], 0, 0, 0);
        acc[a][b2] = __builtin_amdgcn_mfma_f32_16x16x32_bf16(af[a][1], b1, acc[a][b2], 0, 0, 0);
      }
    }
  }

  const int wsel = blockIdx.y / 6;
  const int nloc = (blockIdx.y % 6) * 128;
  if (wsel < 2) {
    unsigned short* Y = wsel ? Yk : Yq;
    const float sc = wsel ? 1.0f : 0.18033688f;   // Q: 0.125 * log2(e)
    #pragma unroll
    for (int fi = 0; fi < 4; ++fi)
      #pragma unroll
      for (int fj = 0; fj < 4; ++fj) {
        const int n = nloc + 64 * wc + 16 * fj + i;
        #pragma unroll
        for (int r = 0; r < 4; ++r) {
          const int m = bm + 64 * wr + 16 * fi + 4 * g + r;
          Y[(size_t)m * Dsz + n] = f2bf_fast(acc[fi][fj][r] * sc);
        }
      }
  } else {
    // V: assemble [n_local 128][t_local 128] bf16 in LDS (XOR swizzle on t),
    // then coalesced 16B writes of the per-head-transposed layout.
    __syncthreads();   // all waves done reading As/Bs
    #pragma unroll
    for (int fi = 0; fi < 4; ++fi)
      #pragma unroll
      for (int fj = 0; fj < 4; ++fj) {
        const int n_l = 64 * wc + 16 * fj + i;
        #pragma unroll
        for (int r = 0; r < 4; ++r) {
          const int t_l = 64 * wr + 16 * fi + 4 * g + r;
          SMEM[n_l * 128 + (t_l ^ ((n_l & 7) << 3))] = f2bf_fast(acc[fi][fj][r]);
        }
      }
    __syncthreads();
    const int n_r = tid >> 1;              // row 0..127
    const int th  = (tid & 1) * 64;        // t-half
    const int n_g = nloc + n_r;
    const int bb  = bm >> 10;
    const int tb  = bm & 1023;
    #pragma unroll
    for (int tc = 0; tc < 8; ++tc) {
      const int t_l = th + tc * 8;
      const uint4 v = *(const uint4*)&SMEM[n_r * 128 + (t_l ^ ((n_r & 7) << 3))];
      *(uint4*)&Yvt[((size_t)(bb * Dsz + n_g)) * Tsz + tb + t_l] = v;
    }
  }
}

// ---------------- output projection: out = ctx * Wp^T + bp, 128x64 tile ----
// grid (64,12) = 768 blocks -> 3 blocks/CU balanced (was 1.5 at 128x128).
__global__ __launch_bounds__(256) void gemm_proj_kernel(
    const unsigned short* __restrict__ X, const unsigned short* __restrict__ W,
    const float* __restrict__ bias, float* __restrict__ Y) {
  __shared__ __align__(16) unsigned short As[128 * 64];  // 16 KB
  __shared__ __align__(16) unsigned short Bs[64 * 64];   // 8 KB
  const int tid = threadIdx.x;
  const int w = tid >> 6, lane = tid & 63;
  const int i = lane & 15, g = lane >> 4;
  const int bm = blockIdx.x * 128, bn = blockIdx.y * 64;
  const int sr = lane >> 3;
  const int scb = ((lane & 7) * 16) ^ (sr << 4);

  f32x4_t acc[2][4];
  #pragma unroll
  for (int a = 0; a < 2; ++a)
    #pragma unroll
    for (int b2 = 0; b2 < 4; ++b2)
      #pragma unroll
      for (int r = 0; r < 4; ++r) acc[a][b2][r] = 0.f;

  for (int k0 = 0; k0 < Dsz; k0 += 64) {
    __syncthreads();
    #pragma unroll
    for (int j = 0; j < 4; ++j) {          // A: 16 chunks, 4 per wave
      const int c = 4 * w + j;
      const int row = 8 * c + sr;          // 0..127
      gload16((const char*)X + ((size_t)(bm + row) * Dsz + k0) * 2 + scb,
              (const char*)As + c * 1024);
    }
    #pragma unroll
    for (int j = 0; j < 2; ++j) {          // B: 8 chunks, 2 per wave
      const int c = 2 * w + j;
      const int row = 8 * c + sr;          // 0..63
      gload16((const char*)W + ((size_t)(bn + row) * Dsz + k0) * 2 + scb,
              (const char*)Bs + c * 1024);
    }
    __syncthreads();
    bf16x8_t af[2][2];
    #pragma unroll
    for (int f = 0; f < 2; ++f) {
      const int R = 32 * w + 16 * f + i;
      #pragma unroll
      for (int kk = 0; kk < 2; ++kk)
        af[f][kk] = *(const bf16x8_t*)((const char*)As + R * 128 +
                                       ((64 * kk + 16 * g) ^ ((i & 7) << 4)));
    }
    #pragma unroll
    for (int b2 = 0; b2 < 4; ++b2) {
      const int R = 16 * b2 + i;
      const bf16x8_t b0 = *(const bf16x8_t*)((const char*)Bs + R * 128 +
                                             ((16 * g) ^ ((i & 7) << 4)));
      const bf16x8_t b1 = *(const bf16x8_t*)((const char*)Bs + R * 128 +
                                             ((64 + 16 * g) ^ ((i & 7) << 4)));
      #pragma unroll
      for (int a = 0; a < 2; ++a) {
        acc[a][b2] = __builtin_amdgcn_mfma_f32_16x16x32_bf16(af[a][0], b0, acc[a][b2], 0, 0, 0);
        acc[a][b2] = __builtin_amdgcn_mfma_f32_16x16x32_bf16(af[a][1], b1, acc[a][b2], 0, 0, 0);
      }
    }
  }

  #pragma unroll
  for (int fi = 0; fi < 2; ++fi)
    #pragma unroll
    for (int fj = 0; fj < 4; ++fj) {
      const int n = bn + 16 * fj + i;
      const float bv = bias[n];
      #pragma unroll
      for (int r = 0; r < 4; ++r) {
        const int m = bm + 32 * w + 16 * fi + 4 * g + r;
        Y[(size_t)m * Dsz + n] = acc[fi][fj][r] + bv;
      }
    }
}

// ---------------- flash attention: 8-wave blocks, BALANCED pairing ---------
__global__ __launch_bounds__(512) void attn_mfma_kernel(
    const unsigned short* __restrict__ Qm, const unsigned short* __restrict__ Km,
    const unsigned short* __restrict__ Vt, unsigned short* __restrict__ ctx) {
  __shared__ __align__(16) unsigned short Ks[2][64 * 64];  // [buf][key][hd]
  __shared__ __align__(16) unsigned short Vs[2][64 * 64];  // [buf][hd][key]
  __shared__ __align__(16) unsigned short Ps[8][16 * 72];  // per-wave P
  const int tid = threadIdx.x, w = tid >> 6, lane = tid & 63;
  const int i = lane & 15, g = lane >> 4;
  const int grp = w >> 2, wl = w & 3;
  const int bh = blockIdx.x, b = bh / Hn, h = bh % Hn;
  const int j = blockIdx.y;
  const int qt = grp ? (NQT - 1 - j) : j;   // A: tile j, B: tile 15-j
  const int t0 = qt * 64;
  const int nkt = NQT - j;                  // loop bound (group B's tiles)

  const int sr  = lane >> 3;
  const int swz = ((lane & 7) * 16) ^ (sr << 4);

  bf16x8_t qa[2];
  {
    const unsigned short* qp =
        Qm + ((size_t)(b * Tsz + t0 + 16 * wl + i) * Dsz + h * 64 + 8 * g);
    qa[0] = *(const bf16x8_t*)qp;
    qa[1] = *(const bf16x8_t*)(qp + 32);
  }

  f32x4_t o[4];
  #pragma unroll
  for (int fd = 0; fd < 4; ++fd)
    #pragma unroll
    for (int r = 0; r < 4; ++r) o[fd][r] = 0.f;
  float mrun[4] = {-3.0e38f, -3.0e38f, -3.0e38f, -3.0e38f};
  float lrun[4] = {0.f, 0.f, 0.f, 0.f};   // per-lane partial row-sums

  auto STAGE = [&](int kv0, int p) {
    const int row = 8 * w + sr;
    gload16((const char*)Km + ((size_t)(b * Tsz + kv0 + row) * Dsz + h * 64) * 2 + swz,
            (const char*)Ks[p] + w * 1024);
    gload16((const char*)Vt + ((size_t)(bh * 64 + row) * Tsz + kv0) * 2 + swz,
            (const char*)Vs[p] + w * 1024);
  };

  STAGE(0, 0);
  unsigned short* Pw = &Ps[w][0];

  for (int kt = 0; kt < nkt; ++kt) {
    const int p = kt & 1;
    __syncthreads();
    if (kt + 1 < nkt) STAGE((kt + 1) * 64, p ^ 1);

    if (kt <= qt) {
      f32x4_t s[4];
      __builtin_amdgcn_s_setprio(1);
      #pragma unroll
      for (int fj = 0; fj < 4; ++fj) {
        #pragma unroll
        for (int r = 0; r < 4; ++r) s[fj][r] = 0.f;
        const int R = 16 * fj + i;
        #pragma unroll
        for (int ks = 0; ks < 2; ++ks) {
          const bf16x8_t kb = *(const bf16x8_t*)((const char*)Ks[p] + R * 128 +
                                                 ((64 * ks + 16 * g) ^ ((i & 7) << 4)));
          s[fj] = __builtin_amdgcn_mfma_f32_16x16x32_bf16(qa[ks], kb, s[fj], 0, 0, 0);
        }
      }
      __builtin_amdgcn_s_setprio(0);

      if (kt == qt) {
        #pragma unroll
        for (int fj = 0; fj < 4; ++fj) {
          const int kidx = kt * 64 + 16 * fj + i;
          #pragma unroll
          for (int r = 0; r < 4; ++r)
            if (kidx > t0 + 16 * wl + 4 * g + r) s[fj][r] = -1.0e30f;
        }
      }

      float mx[4];
      #pragma unroll
      for (int r = 0; r < 4; ++r) {
        float v = fmaxf(fmaxf(s[0][r], s[1][r]), fmaxf(s[2][r], s[3][r]));
        v = fmaxf(v, DPPF(v, 0xB1));
        v = fmaxf(v, DPPF(v, 0x4E));
        v = fmaxf(v, DPPF(v, 0x141));
        v = fmaxf(v, DPPF(v, 0x140));
        mx[r] = v;
      }

      bool nd = false;
      #pragma unroll
      for (int r = 0; r < 4; ++r) nd = nd || (mx[r] > mrun[r] + 8.0f);
      if (__any(nd)) {
        #pragma unroll
        for (int r = 0; r < 4; ++r) {
          const float mn = fmaxf(mrun[r], mx[r]);
          const float fs = exp2f(mrun[r] - mn);
          mrun[r] = mn;
          lrun[r] *= fs;
          #pragma unroll
          for (int fd = 0; fd < 4; ++fd) o[fd][r] *= fs;
        }
      }

      #pragma unroll
      for (int fj = 0; fj < 4; ++fj)
        #pragma unroll
        for (int r = 0; r < 4; ++r) {
          s[fj][r] = exp2f(s[fj][r] - mrun[r]);
          lrun[r] += s[fj][r];
        }

      #pragma unroll
      for (int fj = 0; fj < 4; ++fj)
        #pragma unroll
        for (int r = 0; r < 4; ++r)
          Pw[(4 * g + r) * 72 + 16 * fj + i] = f2bf_fast(s[fj][r]);

      __builtin_amdgcn_s_setprio(1);
      #pragma unroll
      for (int ks = 0; ks < 2; ++ks) {
        const bf16x8_t pa = *(const bf16x8_t*)&Pw[i * 72 + 32 * ks + 8 * g];
        #pragma unroll
        for (int fd = 0; fd < 4; ++fd) {
          const int R = 16 * fd + i;
          const bf16x8_t vb = *(const bf16x8_t*)((const char*)Vs[p] + R * 128 +
                                                 ((64 * ks + 16 * g) ^ ((i & 7) << 4)));
          o[fd] = __builtin_amdgcn_mfma_f32_16x16x32_bf16(pa, vb, o[fd], 0, 0, 0);
        }
      }
      __builtin_amdgcn_s_setprio(0);
    }
  }

  #pragma unroll
  for (int r = 0; r < 4; ++r) {
    float l = lrun[r];
    l += DPPF(l, 0xB1);
    l += DPPF(l, 0x4E);
    l += DPPF(l, 0x141);
    l += DPPF(l, 0x140);
    const float inv = 1.f / l;
    const int qidx = t0 + 16 * wl + 4 * g + r;
    #pragma unroll
    for (int fd = 0; fd < 4; ++fd)
      ctx[(size_t)(b * Tsz + qidx) * Dsz + h * 64 + 16 * fd + i] =
          f2bf_fast(o[fd][r] * inv);
  }
}

extern "C" void kernel_launch(void* const* d_in, const int* in_sizes, int n_in,
                              void* d_out, int out_size, void* d_ws, size_t ws_size,
                              hipStream_t stream) {
  const float* x  = (const float*)d_in[0];
  const float* Wq = (const float*)d_in[1];
  const float* Wk = (const float*)d_in[2];
  const float* Wv = (const float*)d_in[3];
  const float* Wp = (const float*)d_in[4];
  const float* bp = (const float*)d_in[5];
  float* out = (float*)d_out;

  const size_t md = (size_t)Msz * Dsz;
  const size_t wd = (size_t)Dsz * Dsz;
  unsigned short* xb   = (unsigned short*)d_ws;
  unsigned short* wqb  = xb + md;          // wqb,wkb,wvb contiguous = Wcat[2304][768]
  unsigned short* wkb  = wqb + wd;
  unsigned short* wvb  = wkb + wd;
  unsigned short* wpb  = wvb + wd;
  unsigned short* qb   = wpb + wd;
  unsigned short* kb   = qb + md;
  unsigned short* vtb  = kb + md;
  unsigned short* ctxb = vtb + md;

  cvt_all_kernel<<<XBLKS + 4 * WBLKS, 256, 0, stream>>>(
      x, Wq, Wk, Wv, Wp, xb, wqb, wkb, wvb, wpb);

  gemm_qkv_kernel<<<dim3(Msz / 128, 18), 256, 0, stream>>>(xb, wqb, qb, kb, vtb);

  attn_mfma_kernel<<<dim3(Bsz * Hn, 8), 512, 0, stream>>>(qb, kb, vtb, ctxb);

  gemm_proj_kernel<<<dim3(Msz / 128, Dsz / 64), 256, 0, stream>>>(ctxb, wpb, bp, out);
}